// Round 6
// baseline (169.138 us; speedup 1.0000x reference)
//
#include <hip/hip_runtime.h>
#include <math.h>
#include <stdint.h>

#define N 4096
#define Dm 1024
#define BM 128
#define BN 128
#define BK 64
#define NCB (N / 64)   // 64 column-partials per row

typedef __attribute__((ext_vector_type(8))) short bf16x8;
typedef __attribute__((ext_vector_type(4))) int   i32x4;
typedef __attribute__((ext_vector_type(4))) float f32x4;

static __device__ __forceinline__ unsigned short f2bf(float f) {
    unsigned int u = __float_as_uint(f);
    unsigned int r = (u + 0x7fff + ((u >> 16) & 1)) >> 16;  // RNE
    return (unsigned short)r;
}

// Kernel 1: convert A,P -> bf16 + per-row diag dot + L2 partial. Also zeroes the
// fused-final accumulators (poisoned 0xAA before every timed launch).
__global__ __launch_bounds__(256) void prep_kernel(const float* __restrict__ A,
                                                   const float* __restrict__ P,
                                                   unsigned short* __restrict__ Abf,
                                                   unsigned short* __restrict__ Pbf,
                                                   float* __restrict__ D,
                                                   float* __restrict__ rowl2,
                                                   float* __restrict__ accum) {
    int row = blockIdx.x;
    int t = threadIdx.x;                       // 256 threads x float4 = 1024 floats/row
    if (row == 0 && t < 3) accum[t] = 0.0f;    // [0]=loss sum, [1]=l2 sum, [2]=block counter
    const float4* a4 = (const float4*)(A + (size_t)row * Dm);
    const float4* p4 = (const float4*)(P + (size_t)row * Dm);
    float4 a = a4[t], p = p4[t];
    ushort4 ab, pb;
    ab.x = f2bf(a.x); ab.y = f2bf(a.y); ab.z = f2bf(a.z); ab.w = f2bf(a.w);
    pb.x = f2bf(p.x); pb.y = f2bf(p.y); pb.z = f2bf(p.z); pb.w = f2bf(p.w);
    ((ushort4*)(Abf + (size_t)row * Dm))[t] = ab;
    ((ushort4*)(Pbf + (size_t)row * Dm))[t] = pb;
    float dot = a.x * p.x + a.y * p.y + a.z * p.z + a.w * p.w;
    float l2  = a.x * a.x + a.y * a.y + a.z * a.z + a.w * a.w
              + p.x * p.x + p.y * p.y + p.z * p.z + p.w * p.w;
#pragma unroll
    for (int off = 32; off; off >>= 1) {
        dot += __shfl_xor(dot, off, 64);
        l2  += __shfl_xor(l2,  off, 64);
    }
    __shared__ float sd[4], sl[4];
    int wave = t >> 6;
    if ((t & 63) == 0) { sd[wave] = dot; sl[wave] = l2; }
    __syncthreads();
    if (t == 0) {
        D[row]     = sd[0] + sd[1] + sd[2] + sd[3];
        rowl2[row] = sl[0] + sl[1] + sl[2] + sl[3];
    }
}

// Kernel 2: bf16 MFMA GEMM, 128x128 tile, BK=64, XOR-swizzled LDS, REGISTER-PREFETCH
// pipelined K-loop: tile k+1 is loaded global->VGPR while tile k computes; ds_write
// stages it to LDS after the reuse barrier. The vmcnt wait for a tile's loads lands a
// full compute phase after issue -> the per-iteration vmcnt(0) barrier drain (the ~25 us
// stall of the global_load_lds structure at K=1024) is hidden. Fused flash epilogue.
__global__ __launch_bounds__(256) void npair_mfma(const unsigned short* __restrict__ Abf,
                                                  const unsigned short* __restrict__ Pbf,
                                                  const float* __restrict__ D,
                                                  float* __restrict__ Mpart,
                                                  float* __restrict__ Spart) {
    __shared__ unsigned short At[BM * BK];   // 16 KB, row stride 128 B = 32 banks
    __shared__ unsigned short Bt[BN * BK];   // 16 KB
    __shared__ float Ds[BM];
    int tid = threadIdx.x;
    int wid = tid >> 6, lane = tid & 63;
    int wr = wid >> 1, wc = wid & 1;         // 2x2 waves, each owns 64x64 output
    int row0 = blockIdx.y * BM, col0 = blockIdx.x * BN;

    // Loader: 1024 16B-slots per tile; slot L = row*8 + c. Global fetch is STRAIGHT
    // (chunk c of the row); the swizzle c^(row&7) is applied on the LDS WRITE address.
    const unsigned short* gA[4]; const unsigned short* gB[4];
    unsigned short* lA[4]; unsigned short* lB[4];
#pragma unroll
    for (int b = 0; b < 4; ++b) {
        int L = b * 256 + tid;
        int row = L >> 3, c = L & 7;
        gA[b] = Abf + (size_t)(row0 + row) * Dm + (c << 3);
        gB[b] = Pbf + (size_t)(col0 + row) * Dm + (c << 3);
        int sw = c ^ (row & 7);
        lA[b] = At + (size_t)row * BK + (sw << 3);
        lB[b] = Bt + (size_t)row * BK + (sw << 3);
    }
    if (tid < BM) Ds[tid] = D[row0 + tid];

    f32x4 acc[4][4] = {};
    i32x4 ra[4], rb[4];
#pragma unroll
    for (int b = 0; b < 4; ++b) {            // prologue: loads for kt=0
        ra[b] = *(const i32x4*)gA[b];
        rb[b] = *(const i32x4*)gB[b];
    }

    for (int kt = 0; kt < Dm; kt += BK) {    // 16 iterations
        __syncthreads();                      // prior compute's ds_reads done: LDS free
#pragma unroll
        for (int b = 0; b < 4; ++b) {        // stage current tile (waits its own vmcnt,
            *(i32x4*)lA[b] = ra[b];          //  issued a full compute phase ago)
            *(i32x4*)lB[b] = rb[b];
        }
        __syncthreads();                      // LDS tiles ready (lgkm only)
        if (kt + BK < Dm) {
#pragma unroll
            for (int b = 0; b < 4; ++b) {    // prefetch next tile; in flight during compute
                ra[b] = *(const i32x4*)(gA[b] + kt + BK);
                rb[b] = *(const i32x4*)(gB[b] + kt + BK);
            }
        }
#pragma unroll
        for (int ks = 0; ks < 2; ++ks) {
            bf16x8 af[4], bfr[4];
#pragma unroll
            for (int i = 0; i < 4; ++i) {
                int g = (ks << 2) + (lane >> 4);          // global chunk 0..7 in this row
                int arow = wr * 64 + i * 16 + (lane & 15);
                af[i]  = *(const bf16x8*)(At + arow * BK + ((g ^ (arow & 7)) << 3));
                int brow = wc * 64 + i * 16 + (lane & 15);
                bfr[i] = *(const bf16x8*)(Bt + brow * BK + ((g ^ (brow & 7)) << 3));
            }
#pragma unroll
            for (int i = 0; i < 4; ++i)
#pragma unroll
                for (int j = 0; j < 4; ++j)
                    acc[i][j] = __builtin_amdgcn_mfma_f32_16x16x32_bf16(af[i], bfr[j], acc[i][j], 0, 0, 0);
        }
    }

    // Epilogue. C/D layout: col = lane&15, row = (lane>>4)*4 + reg  [m89/m91 verified]
    int cb = blockIdx.x * 2 + wc;            // column-partial slot, NCB=64 per row
#pragma unroll
    for (int rt = 0; rt < 4; ++rt) {
        int rloc = wr * 64 + rt * 16 + ((lane >> 4) << 2);
#pragma unroll
        for (int e = 0; e < 4; ++e) {
            int gr = row0 + rloc + e;
            float Dv = Ds[rloc + e];
            float xs[4];
            float m = -INFINITY;
#pragma unroll
            for (int ct = 0; ct < 4; ++ct) {
                int gc = col0 + wc * 64 + ct * 16 + (lane & 15);
                float x = acc[rt][ct][e] - Dv;
                if (gr == gc) x = -INFINITY;  // mask diagonal
                xs[ct] = x;
                m = fmaxf(m, x);
            }
#pragma unroll
            for (int off = 8; off; off >>= 1) m = fmaxf(m, __shfl_xor(m, off, 64));
            float s = 0.0f;
#pragma unroll
            for (int ct = 0; ct < 4; ++ct) s += __expf(xs[ct] - m);  // exp(-inf)=0 on diag
#pragma unroll
            for (int off = 8; off; off >>= 1) s += __shfl_xor(s, off, 64);
            if ((lane & 15) == 0) {
                Mpart[(size_t)gr * NCB + cb] = m;
                Spart[(size_t)gr * NCB + cb] = s;
            }
        }
    }
}

// Kernel 3 (fused): per-row logsumexp combine + global mean + L2 term.
// 1024 blocks x 4 rows; each block atomically accumulates its loss/l2 partial
// (device-scope), last block finalizes. Counter zeroed by prep_kernel.
__global__ __launch_bounds__(256) void combine_final(const float* __restrict__ Mpart,
                                                     const float* __restrict__ Spart,
                                                     const float* __restrict__ rowl2,
                                                     float* __restrict__ accum,
                                                     float* __restrict__ out) {
    int t = threadIdx.x;
    int lane = t & 63, w = t >> 6;
    int row = blockIdx.x * 4 + w;
    float mp = Mpart[(size_t)row * NCB + lane];
    float sp = Spart[(size_t)row * NCB + lane];
    float m = mp;
#pragma unroll
    for (int off = 32; off; off >>= 1) m = fmaxf(m, __shfl_xor(m, off, 64));
    float s = sp * __expf(mp - m);
#pragma unroll
    for (int off = 32; off; off >>= 1) s += __shfl_xor(s, off, 64);
    __shared__ float ls[4];
    if (lane == 0) ls[w] = m + logf(__expf(-m) + s);   // log1p(sum exp(x)), overflow-safe
    __syncthreads();
    if (t == 0) {
        int r4 = blockIdx.x * 4;
        float L = ls[0] + ls[1] + ls[2] + ls[3];
        float R = rowl2[r4] + rowl2[r4 + 1] + rowl2[r4 + 2] + rowl2[r4 + 3];
        atomicAdd(&accum[0], L);
        atomicAdd(&accum[1], R);
        __threadfence();
        unsigned int old = atomicAdd((unsigned int*)&accum[2], 1u);
        if (old == (unsigned int)(gridDim.x - 1)) {      // last block: finalize
            __threadfence();
            float Lt = atomicAdd(&accum[0], 0.0f);        // coherent read-back
            float Rt = atomicAdd(&accum[1], 0.0f);
            out[0] = Lt / (float)N + 0.02f * (Rt / (float)N);
        }
    }
}

extern "C" void kernel_launch(void* const* d_in, const int* in_sizes, int n_in,
                              void* d_out, int out_size, void* d_ws, size_t ws_size,
                              hipStream_t stream) {
    const float* A = (const float*)d_in[0];
    const float* P = (const float*)d_in[1];
    float* out = (float*)d_out;

    unsigned short* Abf = (unsigned short*)d_ws;            // N*Dm bf16 = 8 MiB
    unsigned short* Pbf = Abf + (size_t)N * Dm;             // 8 MiB
    float* D     = (float*)(Pbf + (size_t)N * Dm);          // N
    float* rowl2 = D + N;                                   // N
    float* accum = rowl2 + N;                               // 3 (+pad)
    float* Mpart = accum + 64;                              // N*NCB = 1 MiB
    float* Spart = Mpart + (size_t)N * NCB;                 // 1 MiB

    prep_kernel<<<N, 256, 0, stream>>>(A, P, Abf, Pbf, D, rowl2, accum);
    dim3 grid(N / BN, N / BM);
    npair_mfma<<<grid, 256, 0, stream>>>(Abf, Pbf, D, Mpart, Spart);
    combine_final<<<N / 4, 256, 0, stream>>>(Mpart, Spart, rowl2, accum, out);
}

// Round 7
// 135.505 us; speedup vs baseline: 1.2482x; 1.2482x over previous
//
#include <hip/hip_runtime.h>
#include <math.h>
#include <stdint.h>

#define N 4096
#define Dm 1024
#define BM 128
#define BN 128
#define BK 32
#define NCB (N / 64)   // 64 column-partials per row

typedef __attribute__((ext_vector_type(8))) short bf16x8;
typedef __attribute__((ext_vector_type(4))) float f32x4;

typedef const void __attribute__((address_space(1)))* gas_t;
typedef void __attribute__((address_space(3)))* las_t;

static __device__ __forceinline__ void gload_lds16(const void* g, void* l) {
    // async global->LDS, 16B per lane; LDS dest is wave-uniform base + lane*16
    __builtin_amdgcn_global_load_lds((gas_t)g, (las_t)l, 16, 0, 0);
}

static __device__ __forceinline__ unsigned short f2bf(float f) {
    unsigned int u = __float_as_uint(f);
    unsigned int r = (u + 0x7fff + ((u >> 16) & 1)) >> 16;  // RNE
    return (unsigned short)r;
}

// Kernel 1: convert A,P -> bf16 + per-row diag dot + L2 partial.
__global__ __launch_bounds__(256) void prep_kernel(const float* __restrict__ A,
                                                   const float* __restrict__ P,
                                                   unsigned short* __restrict__ Abf,
                                                   unsigned short* __restrict__ Pbf,
                                                   float* __restrict__ D,
                                                   float* __restrict__ rowl2) {
    int row = blockIdx.x;
    int t = threadIdx.x;                       // 256 threads x float4 = 1024 floats/row
    const float4* a4 = (const float4*)(A + (size_t)row * Dm);
    const float4* p4 = (const float4*)(P + (size_t)row * Dm);
    float4 a = a4[t], p = p4[t];
    ushort4 ab, pb;
    ab.x = f2bf(a.x); ab.y = f2bf(a.y); ab.z = f2bf(a.z); ab.w = f2bf(a.w);
    pb.x = f2bf(p.x); pb.y = f2bf(p.y); pb.z = f2bf(p.z); pb.w = f2bf(p.w);
    ((ushort4*)(Abf + (size_t)row * Dm))[t] = ab;
    ((ushort4*)(Pbf + (size_t)row * Dm))[t] = pb;
    float dot = a.x * p.x + a.y * p.y + a.z * p.z + a.w * p.w;
    float l2  = a.x * a.x + a.y * a.y + a.z * a.z + a.w * a.w
              + p.x * p.x + p.y * p.y + p.z * p.z + p.w * p.w;
#pragma unroll
    for (int off = 32; off; off >>= 1) {
        dot += __shfl_xor(dot, off, 64);
        l2  += __shfl_xor(l2,  off, 64);
    }
    __shared__ float sd[4], sl[4];
    int wave = t >> 6;
    if ((t & 63) == 0) { sd[wave] = dot; sl[wave] = l2; }
    __syncthreads();
    if (t == 0) {
        D[row]     = sd[0] + sd[1] + sd[2] + sd[3];
        rowl2[row] = sl[0] + sl[1] + sl[2] + sl[3];
    }
}

// Kernel 2: bf16 MFMA GEMM, 128x128 tile, BK=32, DOUBLE-BUFFERED global_load_lds with
// ONE barrier per K-iteration: loads for tile k+1 are issued immediately after the
// barrier (into the just-freed buffer), so the vmcnt drain at the NEXT barrier lands a
// full compute phase after issue. 2x16 KB LDS keeps 4 blocks/CU. Swizzle: global chunk
// g stored at position g^((row>>1)&3) (64B row stride -> 2-way bank aliasing = free);
// LDS write side stays lane-ordered (gload_lds constraint), swizzle is in the global
// fetch address. Fused flash-style epilogue (m89/m91-verified C/D layout).
__global__ __launch_bounds__(256) void npair_mfma(const unsigned short* __restrict__ Abf,
                                                  const unsigned short* __restrict__ Pbf,
                                                  const float* __restrict__ D,
                                                  float* __restrict__ Mpart,
                                                  float* __restrict__ Spart) {
    __shared__ unsigned short At[2][BM * BK];   // 2 x 8 KB
    __shared__ unsigned short Bt[2][BN * BK];   // 2 x 8 KB
    __shared__ float Ds[BM];
    int tid = threadIdx.x;
    int wid = tid >> 6, lane = tid & 63;
    int wr = wid >> 1, wc = wid & 1;            // 2x2 waves, each owns 64x64 output
    int row0 = blockIdx.y * BM, col0 = blockIdx.x * BN;

    // Loader: 512 16B-slots per matrix per buffer; slot L = row*4 + c holds global
    // chunk g = c ^ ((row>>1)&3). Two issues (b=0,1) per matrix per iteration.
    const unsigned short* gA[2]; const unsigned short* gB[2];
    int loff[2];
#pragma unroll
    for (int b = 0; b < 2; ++b) {
        int L = b * 256 + tid;
        int row = L >> 2, c = L & 3;
        int g = c ^ ((row >> 1) & 3);
        gA[b] = Abf + (size_t)(row0 + row) * Dm + (g << 3);
        gB[b] = Pbf + (size_t)(col0 + row) * Dm + (g << 3);
        loff[b] = L * 8;                         // ushort offset of slot L (16B each)
    }
    if (tid < BM) Ds[tid] = D[row0 + tid];

    f32x4 acc[4][4] = {};

    // Prologue: load tile 0 into buffer 0.
#pragma unroll
    for (int b = 0; b < 2; ++b) {
        gload_lds16(gA[b], At[0] + loff[b]);
        gload_lds16(gB[b], Bt[0] + loff[b]);
    }

    int p = 0;
    for (int kt = 0; kt < Dm; kt += BK) {       // 32 iterations, ONE barrier each
        __syncthreads();   // (a) drains vmcnt -> buf[p] landed; (b) all waves done
                           //     reading buf[p^1] from the previous iteration
        if (kt + BK < Dm) {
#pragma unroll
            for (int b = 0; b < 2; ++b) {        // prefetch next tile into freed buffer;
                gload_lds16(gA[b] + kt + BK, At[p ^ 1] + loff[b]);
                gload_lds16(gB[b] + kt + BK, Bt[p ^ 1] + loff[b]);
            }
        }
        const unsigned short* Ab = At[p];
        const unsigned short* Bb = Bt[p];
        bf16x8 af[4], bfr[4];
        int g = lane >> 4;                       // this lane's global 16B chunk, 0..3
#pragma unroll
        for (int i = 0; i < 4; ++i) {
            int arow = wr * 64 + i * 16 + (lane & 15);
            af[i]  = *(const bf16x8*)(Ab + arow * BK + ((g ^ ((arow >> 1) & 3)) << 3));
            int brow = wc * 64 + i * 16 + (lane & 15);
            bfr[i] = *(const bf16x8*)(Bb + brow * BK + ((g ^ ((brow >> 1) & 3)) << 3));
        }
#pragma unroll
        for (int i = 0; i < 4; ++i)
#pragma unroll
            for (int j = 0; j < 4; ++j)
                acc[i][j] = __builtin_amdgcn_mfma_f32_16x16x32_bf16(af[i], bfr[j], acc[i][j], 0, 0, 0);
        p ^= 1;
    }

    // Epilogue. C/D layout: col = lane&15, row = (lane>>4)*4 + reg  [m89/m91 verified]
    int cb = blockIdx.x * 2 + wc;               // column-partial slot, NCB=64 per row
#pragma unroll
    for (int rt = 0; rt < 4; ++rt) {
        int rloc = wr * 64 + rt * 16 + ((lane >> 4) << 2);
#pragma unroll
        for (int e = 0; e < 4; ++e) {
            int gr = row0 + rloc + e;
            float Dv = Ds[rloc + e];
            float xs[4];
            float m = -INFINITY;
#pragma unroll
            for (int ct = 0; ct < 4; ++ct) {
                int gc = col0 + wc * 64 + ct * 16 + (lane & 15);
                float x = acc[rt][ct][e] - Dv;
                if (gr == gc) x = -INFINITY;    // mask diagonal
                xs[ct] = x;
                m = fmaxf(m, x);
            }
#pragma unroll
            for (int off = 8; off; off >>= 1) m = fmaxf(m, __shfl_xor(m, off, 64));
            float s = 0.0f;
#pragma unroll
            for (int ct = 0; ct < 4; ++ct) s += __expf(xs[ct] - m);  // exp(-inf)=0 on diag
#pragma unroll
            for (int off = 8; off; off >>= 1) s += __shfl_xor(s, off, 64);
            if ((lane & 15) == 0) {
                Mpart[(size_t)gr * NCB + cb] = m;
                Spart[(size_t)gr * NCB + cb] = s;
            }
        }
    }
}

// Kernel 3: combine partials per row (no cross-XCD atomics — round-6 lesson).
__global__ __launch_bounds__(256) void combine_rows(const float* __restrict__ Mpart,
                                                    const float* __restrict__ Spart,
                                                    float* __restrict__ loss) {
    int t = threadIdx.x;
    int lane = t & 63;
    int row = blockIdx.x * 4 + (t >> 6);
    float mp = Mpart[(size_t)row * NCB + lane];
    float sp = Spart[(size_t)row * NCB + lane];
    float m = mp;
#pragma unroll
    for (int off = 32; off; off >>= 1) m = fmaxf(m, __shfl_xor(m, off, 64));
    float s = sp * __expf(mp - m);
#pragma unroll
    for (int off = 32; off; off >>= 1) s += __shfl_xor(s, off, 64);
    if (lane == 0) loss[row] = m + logf(__expf(-m) + s);   // log1p(sum exp(x)), overflow-safe
}

// Kernel 4: final scalar: mean(loss) + 0.02 * sum(rowl2)/N
__global__ __launch_bounds__(256) void final_reduce(const float* __restrict__ loss,
                                                    const float* __restrict__ rowl2,
                                                    float* __restrict__ out) {
    int t = threadIdx.x;
    float accL = 0.0f, acc2 = 0.0f;
    for (int i = t; i < N; i += 256) {
        accL += loss[i];
        acc2 += rowl2[i];
    }
#pragma unroll
    for (int off = 32; off; off >>= 1) {
        accL += __shfl_xor(accL, off, 64);
        acc2 += __shfl_xor(acc2, off, 64);
    }
    __shared__ float sa[4], sb[4];
    int wave = t >> 6;
    if ((t & 63) == 0) { sa[wave] = accL; sb[wave] = acc2; }
    __syncthreads();
    if (t == 0) {
        float L  = sa[0] + sa[1] + sa[2] + sa[3];
        float l2 = sb[0] + sb[1] + sb[2] + sb[3];
        out[0] = L / (float)N + 0.02f * (l2 / (float)N);
    }
}

extern "C" void kernel_launch(void* const* d_in, const int* in_sizes, int n_in,
                              void* d_out, int out_size, void* d_ws, size_t ws_size,
                              hipStream_t stream) {
    const float* A = (const float*)d_in[0];
    const float* P = (const float*)d_in[1];
    float* out = (float*)d_out;

    unsigned short* Abf = (unsigned short*)d_ws;            // N*Dm bf16 = 8 MiB
    unsigned short* Pbf = Abf + (size_t)N * Dm;             // 8 MiB
    float* D     = (float*)(Pbf + (size_t)N * Dm);          // N
    float* rowl2 = D + N;                                   // N
    float* loss  = rowl2 + N;                               // N
    float* Mpart = loss + N;                                // N*NCB = 1 MiB
    float* Spart = Mpart + (size_t)N * NCB;                 // 1 MiB

    prep_kernel<<<N, 256, 0, stream>>>(A, P, Abf, Pbf, D, rowl2);
    dim3 grid(N / BN, N / BM);
    npair_mfma<<<grid, 256, 0, stream>>>(Abf, Pbf, D, Mpart, Spart);
    combine_rows<<<N / 4, 256, 0, stream>>>(Mpart, Spart, loss);
    final_reduce<<<1, 256, 0, stream>>>(loss, rowl2, out);
}

// Round 8
// 131.720 us; speedup vs baseline: 1.2841x; 1.0287x over previous
//
#include <hip/hip_runtime.h>
#include <math.h>
#include <stdint.h>

#define N 4096
#define Dm 1024
#define BM 128
#define BN 128
#define BK 64
#define NCB (N / 64)   // 64 column-partials per row

typedef __attribute__((ext_vector_type(8))) short bf16x8;
typedef __attribute__((ext_vector_type(4))) float f32x4;

typedef const void __attribute__((address_space(1)))* gas_t;
typedef void __attribute__((address_space(3)))* las_t;

static __device__ __forceinline__ void gload_lds16(const void* g, void* l) {
    // async global->LDS, 16B per lane; LDS dest is wave-uniform base + lane*16
    __builtin_amdgcn_global_load_lds((gas_t)g, (las_t)l, 16, 0, 0);
}

static __device__ __forceinline__ unsigned short f2bf(float f) {
    unsigned int u = __float_as_uint(f);
    unsigned int r = (u + 0x7fff + ((u >> 16) & 1)) >> 16;  // RNE
    return (unsigned short)r;
}

// Kernel 1: convert A,P -> bf16 + per-row diag dot + L2 partial.
// One wave per row: lane reads 16 floats of each matrix (4x float4), 6-shuffle reduce,
// no LDS round-trip. 1024 blocks x 256 threads (4 rows/block).
__global__ __launch_bounds__(256) void prep_kernel(const float* __restrict__ A,
                                                   const float* __restrict__ P,
                                                   unsigned short* __restrict__ Abf,
                                                   unsigned short* __restrict__ Pbf,
                                                   float* __restrict__ D,
                                                   float* __restrict__ rowl2) {
    int t = threadIdx.x;
    int lane = t & 63;
    int row = blockIdx.x * 4 + (t >> 6);
    const float4* a4 = (const float4*)(A + (size_t)row * Dm);
    const float4* p4 = (const float4*)(P + (size_t)row * Dm);
    ushort4* ao = (ushort4*)(Abf + (size_t)row * Dm);
    ushort4* po = (ushort4*)(Pbf + (size_t)row * Dm);
    float dot = 0.0f, l2 = 0.0f;
#pragma unroll
    for (int c = 0; c < 4; ++c) {
        int idx = c * 64 + lane;              // coalesced within the wave
        float4 a = a4[idx], p = p4[idx];
        ushort4 ab, pb;
        ab.x = f2bf(a.x); ab.y = f2bf(a.y); ab.z = f2bf(a.z); ab.w = f2bf(a.w);
        pb.x = f2bf(p.x); pb.y = f2bf(p.y); pb.z = f2bf(p.z); pb.w = f2bf(p.w);
        ao[idx] = ab; po[idx] = pb;
        dot += a.x * p.x + a.y * p.y + a.z * p.z + a.w * p.w;
        l2  += a.x * a.x + a.y * a.y + a.z * a.z + a.w * a.w
             + p.x * p.x + p.y * p.y + p.z * p.z + p.w * p.w;
    }
#pragma unroll
    for (int off = 32; off; off >>= 1) {
        dot += __shfl_xor(dot, off, 64);
        l2  += __shfl_xor(l2,  off, 64);
    }
    if (lane == 0) {
        D[row]     = dot;
        rowl2[row] = l2;
    }
}

// Kernel 2 (R4 version — best measured: 53.3 us, 0 bank conflicts): bf16 MFMA GEMM,
// 128x128 tile, BK=64, XOR-swizzled LDS (global chunk c fetched into position
// c^(row&7): conflict-free ds_read_b128), global_load_lds(16B) staging, fused
// flash-style epilogue. R6/R7 confirmed source-level pipelining variants are
// neutral-to-negative (m97-structure plateau at K=1024) — do not re-litigate.
__global__ __launch_bounds__(256) void npair_mfma(const unsigned short* __restrict__ Abf,
                                                  const unsigned short* __restrict__ Pbf,
                                                  const float* __restrict__ D,
                                                  float* __restrict__ Mpart,
                                                  float* __restrict__ Spart) {
    __shared__ unsigned short At[BM * BK];   // 16 KB, row stride 128 B = 32 banks
    __shared__ unsigned short Bt[BN * BK];   // 16 KB
    __shared__ float Ds[BM];
    int tid = threadIdx.x;
    int wid = tid >> 6, lane = tid & 63;
    int wr = wid >> 1, wc = wid & 1;         // 2x2 waves, each owns 64x64 output
    int row0 = blockIdx.y * BM, col0 = blockIdx.x * BN;

    // Loader: 1024 slots of 16B per tile; slot L = row*8 + c holds global k-chunk
    // (c^(row&7)). Swizzle applied in the GLOBAL fetch address; LDS dest lane-ordered.
    const unsigned short* gA[4]; const unsigned short* gB[4];
    unsigned short* lA[4]; unsigned short* lB[4];
#pragma unroll
    for (int b = 0; b < 4; ++b) {
        int L = b * 256 + tid;
        int row = L >> 3, c = L & 7;
        int kch = c ^ (row & 7);
        gA[b] = Abf + (size_t)(row0 + row) * Dm + (kch << 3);
        gB[b] = Pbf + (size_t)(col0 + row) * Dm + (kch << 3);
        lA[b] = At + (size_t)L * 8;
        lB[b] = Bt + (size_t)L * 8;
    }
    if (tid < BM) Ds[tid] = D[row0 + tid];

    f32x4 acc[4][4] = {};

    for (int kt = 0; kt < Dm; kt += BK) {    // 16 iterations
        __syncthreads();                      // prior frag reads done before overwrite
#pragma unroll
        for (int b = 0; b < 4; ++b) {
            gload_lds16(gA[b] + kt, lA[b]);
            gload_lds16(gB[b] + kt, lB[b]);
        }
        __syncthreads();                      // drains vmcnt(0): LDS tiles ready
#pragma unroll
        for (int ks = 0; ks < 2; ++ks) {
            bf16x8 af[4], bfr[4];
#pragma unroll
            for (int i = 0; i < 4; ++i) {
                int g = (ks << 2) + (lane >> 4);          // global chunk 0..7 in this row
                int arow = wr * 64 + i * 16 + (lane & 15);
                af[i]  = *(const bf16x8*)(At + arow * BK + ((g ^ (arow & 7)) << 3));
                int brow = wc * 64 + i * 16 + (lane & 15);
                bfr[i] = *(const bf16x8*)(Bt + brow * BK + ((g ^ (brow & 7)) << 3));
            }
#pragma unroll
            for (int i = 0; i < 4; ++i)
#pragma unroll
                for (int j = 0; j < 4; ++j)
                    acc[i][j] = __builtin_amdgcn_mfma_f32_16x16x32_bf16(af[i], bfr[j], acc[i][j], 0, 0, 0);
        }
    }

    // Epilogue. C/D layout: col = lane&15, row = (lane>>4)*4 + reg  [m89/m91 verified]
    int cb = blockIdx.x * 2 + wc;            // column-partial slot, NCB=64 per row
#pragma unroll
    for (int rt = 0; rt < 4; ++rt) {
        int rloc = wr * 64 + rt * 16 + ((lane >> 4) << 2);
#pragma unroll
        for (int e = 0; e < 4; ++e) {
            int gr = row0 + rloc + e;
            float Dv = Ds[rloc + e];
            float xs[4];
            float m = -INFINITY;
#pragma unroll
            for (int ct = 0; ct < 4; ++ct) {
                int gc = col0 + wc * 64 + ct * 16 + (lane & 15);
                float x = acc[rt][ct][e] - Dv;
                if (gr == gc) x = -INFINITY;  // mask diagonal
                xs[ct] = x;
                m = fmaxf(m, x);
            }
#pragma unroll
            for (int off = 8; off; off >>= 1) m = fmaxf(m, __shfl_xor(m, off, 64));
            float s = 0.0f;
#pragma unroll
            for (int ct = 0; ct < 4; ++ct) s += __expf(xs[ct] - m);  // exp(-inf)=0 on diag
#pragma unroll
            for (int off = 8; off; off >>= 1) s += __shfl_xor(s, off, 64);
            if ((lane & 15) == 0) {
                Mpart[(size_t)gr * NCB + cb] = m;
                Spart[(size_t)gr * NCB + cb] = s;
            }
        }
    }
}

// Kernel 3: combine partials per row (2 rows per wave sequentially, 512 blocks).
__global__ __launch_bounds__(256) void combine_rows(const float* __restrict__ Mpart,
                                                    const float* __restrict__ Spart,
                                                    float* __restrict__ loss) {
    int t = threadIdx.x;
    int lane = t & 63;
    int w = t >> 6;
#pragma unroll
    for (int r = 0; r < 2; ++r) {
        int row = blockIdx.x * 8 + w * 2 + r;
        float mp = Mpart[(size_t)row * NCB + lane];
        float sp = Spart[(size_t)row * NCB + lane];
        float m = mp;
#pragma unroll
        for (int off = 32; off; off >>= 1) m = fmaxf(m, __shfl_xor(m, off, 64));
        float s = sp * __expf(mp - m);
#pragma unroll
        for (int off = 32; off; off >>= 1) s += __shfl_xor(s, off, 64);
        if (lane == 0) loss[row] = m + logf(__expf(-m) + s);  // log1p(sum exp), safe
    }
}

// Kernel 4: final scalar: mean(loss) + 0.02 * sum(rowl2)/N
__global__ __launch_bounds__(256) void final_reduce(const float* __restrict__ loss,
                                                    const float* __restrict__ rowl2,
                                                    float* __restrict__ out) {
    int t = threadIdx.x;
    float accL = 0.0f, acc2 = 0.0f;
    for (int i = t; i < N; i += 256) {
        accL += loss[i];
        acc2 += rowl2[i];
    }
#pragma unroll
    for (int off = 32; off; off >>= 1) {
        accL += __shfl_xor(accL, off, 64);
        acc2 += __shfl_xor(acc2, off, 64);
    }
    __shared__ float sa[4], sb[4];
    int wave = t >> 6;
    if ((t & 63) == 0) { sa[wave] = accL; sb[wave] = acc2; }
    __syncthreads();
    if (t == 0) {
        float L  = sa[0] + sa[1] + sa[2] + sa[3];
        float l2 = sb[0] + sb[1] + sb[2] + sb[3];
        out[0] = L / (float)N + 0.02f * (l2 / (float)N);
    }
}

extern "C" void kernel_launch(void* const* d_in, const int* in_sizes, int n_in,
                              void* d_out, int out_size, void* d_ws, size_t ws_size,
                              hipStream_t stream) {
    const float* A = (const float*)d_in[0];
    const float* P = (const float*)d_in[1];
    float* out = (float*)d_out;

    unsigned short* Abf = (unsigned short*)d_ws;            // N*Dm bf16 = 8 MiB
    unsigned short* Pbf = Abf + (size_t)N * Dm;             // 8 MiB
    float* D     = (float*)(Pbf + (size_t)N * Dm);          // N
    float* rowl2 = D + N;                                   // N
    float* loss  = rowl2 + N;                               // N
    float* Mpart = loss + N;                                // N*NCB = 1 MiB
    float* Spart = Mpart + (size_t)N * NCB;                 // 1 MiB

    prep_kernel<<<N / 4, 256, 0, stream>>>(A, P, Abf, Pbf, D, rowl2);
    dim3 grid(N / BN, N / BM);
    npair_mfma<<<grid, 256, 0, stream>>>(Abf, Pbf, D, Mpart, Spart);
    combine_rows<<<N / 8, 256, 0, stream>>>(Mpart, Spart, loss);
    final_reduce<<<1, 256, 0, stream>>>(loss, rowl2, out);
}

// Round 9
// 124.962 us; speedup vs baseline: 1.3535x; 1.0541x over previous
//
#include <hip/hip_runtime.h>
#include <math.h>
#include <stdint.h>

#define N 4096
#define Dm 1024
#define BM 128
#define BN 128
#define BK 64
#define NCB (N / 64)   // 64 column-partials per row
#define NPART 512      // combine blocks -> scalar partials

typedef __attribute__((ext_vector_type(8))) short bf16x8;
typedef __attribute__((ext_vector_type(4))) float f32x4;

typedef const void __attribute__((address_space(1)))* gas_t;
typedef void __attribute__((address_space(3)))* las_t;

static __device__ __forceinline__ void gload_lds16(const void* g, void* l) {
    // async global->LDS, 16B per lane; LDS dest is wave-uniform base + lane*16
    __builtin_amdgcn_global_load_lds((gas_t)g, (las_t)l, 16, 0, 0);
}

static __device__ __forceinline__ unsigned short f2bf(float f) {
    unsigned int u = __float_as_uint(f);
    unsigned int r = (u + 0x7fff + ((u >> 16) & 1)) >> 16;  // RNE
    return (unsigned short)r;
}

// Kernel 1: convert A,P -> bf16 + per-row diag dot + L2 partial. One wave per row.
__global__ __launch_bounds__(256) void prep_kernel(const float* __restrict__ A,
                                                   const float* __restrict__ P,
                                                   unsigned short* __restrict__ Abf,
                                                   unsigned short* __restrict__ Pbf,
                                                   float* __restrict__ D,
                                                   float* __restrict__ rowl2) {
    int t = threadIdx.x;
    int lane = t & 63;
    int row = blockIdx.x * 4 + (t >> 6);
    const float4* a4 = (const float4*)(A + (size_t)row * Dm);
    const float4* p4 = (const float4*)(P + (size_t)row * Dm);
    ushort4* ao = (ushort4*)(Abf + (size_t)row * Dm);
    ushort4* po = (ushort4*)(Pbf + (size_t)row * Dm);
    float dot = 0.0f, l2 = 0.0f;
#pragma unroll
    for (int c = 0; c < 4; ++c) {
        int idx = c * 64 + lane;              // coalesced within the wave
        float4 a = a4[idx], p = p4[idx];
        ushort4 ab, pb;
        ab.x = f2bf(a.x); ab.y = f2bf(a.y); ab.z = f2bf(a.z); ab.w = f2bf(a.w);
        pb.x = f2bf(p.x); pb.y = f2bf(p.y); pb.z = f2bf(p.z); pb.w = f2bf(p.w);
        ao[idx] = ab; po[idx] = pb;
        dot += a.x * p.x + a.y * p.y + a.z * p.z + a.w * p.w;
        l2  += a.x * a.x + a.y * a.y + a.z * a.z + a.w * a.w
             + p.x * p.x + p.y * p.y + p.z * p.z + p.w * p.w;
    }
#pragma unroll
    for (int off = 32; off; off >>= 1) {
        dot += __shfl_xor(dot, off, 64);
        l2  += __shfl_xor(l2,  off, 64);
    }
    if (lane == 0) {
        D[row]     = dot;
        rowl2[row] = l2;
    }
}

// Kernel 2 (R4/R8 plateau version + XCD-aware block swizzle): bf16 MFMA GEMM,
// 128x128 tile, BK=64, XOR-swizzled LDS (conflict-free), global_load_lds(16B),
// fused flash-style epilogue. K-loop structure is at the measured HIP-source
// plateau (R4=53.3, R6/R7 + m99-m141 variants all neutral/worse) — frozen.
__global__ __launch_bounds__(256) void npair_mfma(const unsigned short* __restrict__ Abf,
                                                  const unsigned short* __restrict__ Pbf,
                                                  const float* __restrict__ D,
                                                  float* __restrict__ Mpart,
                                                  float* __restrict__ Spart) {
    __shared__ unsigned short At[BM * BK];   // 16 KB, row stride 128 B = 32 banks
    __shared__ unsigned short Bt[BN * BK];   // 16 KB
    __shared__ float Ds[BM];
    int tid = threadIdx.x;
    int wid = tid >> 6, lane = tid & 63;
    int wr = wid >> 1, wc = wid & 1;         // 2x2 waves, each owns 64x64 output

    // XCD-aware swizzle: 1024 blocks -> 8 XCDs (round-robin on linear id), each XCD
    // gets a compact 16x8 patch of the 32x32 tile grid (tighter L2 working set ->
    // lower load latency -> smaller per-barrier drain). Pure re-labeling.
    int bid = blockIdx.y * gridDim.x + blockIdx.x;
    int xcd = bid & 7, lid = bid >> 3;       // lid in [0,128)
    int by = (xcd >> 2) * 16 + (lid >> 3);   // [0,32)
    int bx = (xcd & 3) * 8 + (lid & 7);      // [0,32)
    int row0 = by * BM, col0 = bx * BN;

    // Loader: 1024 slots of 16B per tile; slot L = row*8 + c holds global k-chunk
    // (c^(row&7)). Swizzle applied in the GLOBAL fetch address; LDS dest lane-ordered.
    const unsigned short* gA[4]; const unsigned short* gB[4];
    unsigned short* lA[4]; unsigned short* lB[4];
#pragma unroll
    for (int b = 0; b < 4; ++b) {
        int L = b * 256 + tid;
        int row = L >> 3, c = L & 7;
        int kch = c ^ (row & 7);
        gA[b] = Abf + (size_t)(row0 + row) * Dm + (kch << 3);
        gB[b] = Pbf + (size_t)(col0 + row) * Dm + (kch << 3);
        lA[b] = At + (size_t)L * 8;
        lB[b] = Bt + (size_t)L * 8;
    }
    if (tid < BM) Ds[tid] = D[row0 + tid];

    f32x4 acc[4][4] = {};

    for (int kt = 0; kt < Dm; kt += BK) {    // 16 iterations
        __syncthreads();                      // prior frag reads done before overwrite
#pragma unroll
        for (int b = 0; b < 4; ++b) {
            gload_lds16(gA[b] + kt, lA[b]);
            gload_lds16(gB[b] + kt, lB[b]);
        }
        __syncthreads();                      // drains vmcnt(0): LDS tiles ready
#pragma unroll
        for (int ks = 0; ks < 2; ++ks) {
            bf16x8 af[4], bfr[4];
#pragma unroll
            for (int i = 0; i < 4; ++i) {
                int g = (ks << 2) + (lane >> 4);          // global chunk 0..7 in this row
                int arow = wr * 64 + i * 16 + (lane & 15);
                af[i]  = *(const bf16x8*)(At + arow * BK + ((g ^ (arow & 7)) << 3));
                int brow = wc * 64 + i * 16 + (lane & 15);
                bfr[i] = *(const bf16x8*)(Bt + brow * BK + ((g ^ (brow & 7)) << 3));
            }
#pragma unroll
            for (int i = 0; i < 4; ++i)
#pragma unroll
                for (int j = 0; j < 4; ++j)
                    acc[i][j] = __builtin_amdgcn_mfma_f32_16x16x32_bf16(af[i], bfr[j], acc[i][j], 0, 0, 0);
        }
    }

    // Epilogue. C/D layout: col = lane&15, row = (lane>>4)*4 + reg  [m89/m91 verified]
    int cb = bx * 2 + wc;                    // column-partial slot, NCB=64 per row
#pragma unroll
    for (int rt = 0; rt < 4; ++rt) {
        int rloc = wr * 64 + rt * 16 + ((lane >> 4) << 2);
#pragma unroll
        for (int e = 0; e < 4; ++e) {
            int gr = row0 + rloc + e;
            float Dv = Ds[rloc + e];
            float xs[4];
            float m = -INFINITY;
#pragma unroll
            for (int ct = 0; ct < 4; ++ct) {
                int gc = col0 + wc * 64 + ct * 16 + (lane & 15);
                float x = acc[rt][ct][e] - Dv;
                if (gr == gc) x = -INFINITY;  // mask diagonal
                xs[ct] = x;
                m = fmaxf(m, x);
            }
#pragma unroll
            for (int off = 8; off; off >>= 1) m = fmaxf(m, __shfl_xor(m, off, 64));
            float s = 0.0f;
#pragma unroll
            for (int ct = 0; ct < 4; ++ct) s += __expf(xs[ct] - m);  // exp(-inf)=0 on diag
#pragma unroll
            for (int off = 8; off; off >>= 1) s += __shfl_xor(s, off, 64);
            if ((lane & 15) == 0) {
                Mpart[(size_t)gr * NCB + cb] = m;
                Spart[(size_t)gr * NCB + cb] = s;
            }
        }
    }
}

// Kernel 3: per-row logsumexp combine; each block (8 rows) emits ONE partial pair
// (sum of loss over its rows, sum of rowl2) -> 512 pairs. No cross-XCD atomics.
__global__ __launch_bounds__(256) void combine_rows(const float* __restrict__ Mpart,
                                                    const float* __restrict__ Spart,
                                                    const float* __restrict__ rowl2,
                                                    float* __restrict__ partL,
                                                    float* __restrict__ partR) {
    int t = threadIdx.x;
    int lane = t & 63;
    int w = t >> 6;
    __shared__ float ls[8];
#pragma unroll
    for (int r = 0; r < 2; ++r) {
        int row = blockIdx.x * 8 + w * 2 + r;
        float mp = Mpart[(size_t)row * NCB + lane];
        float sp = Spart[(size_t)row * NCB + lane];
        float m = mp;
#pragma unroll
        for (int off = 32; off; off >>= 1) m = fmaxf(m, __shfl_xor(m, off, 64));
        float s = sp * __expf(mp - m);
#pragma unroll
        for (int off = 32; off; off >>= 1) s += __shfl_xor(s, off, 64);
        if (lane == 0) ls[w * 2 + r] = m + logf(__expf(-m) + s);  // log1p(sum exp), safe
    }
    __syncthreads();
    if (t == 0) {
        int r8 = blockIdx.x * 8;
        float L = 0.0f, R = 0.0f;
#pragma unroll
        for (int r = 0; r < 8; ++r) { L += ls[r]; R += rowl2[r8 + r]; }
        partL[blockIdx.x] = L;
        partR[blockIdx.x] = R;
    }
}

// Kernel 4: final scalar from 512 partial pairs.
__global__ __launch_bounds__(256) void final_reduce(const float* __restrict__ partL,
                                                    const float* __restrict__ partR,
                                                    float* __restrict__ out) {
    int t = threadIdx.x;
    float accL = partL[t] + partL[t + 256];
    float acc2 = partR[t] + partR[t + 256];
#pragma unroll
    for (int off = 32; off; off >>= 1) {
        accL += __shfl_xor(accL, off, 64);
        acc2 += __shfl_xor(acc2, off, 64);
    }
    __shared__ float sa[4], sb[4];
    int wave = t >> 6;
    if ((t & 63) == 0) { sa[wave] = accL; sb[wave] = acc2; }
    __syncthreads();
    if (t == 0) {
        float L  = sa[0] + sa[1] + sa[2] + sa[3];
        float l2 = sb[0] + sb[1] + sb[2] + sb[3];
        out[0] = L / (float)N + 0.02f * (l2 / (float)N);
    }
}

extern "C" void kernel_launch(void* const* d_in, const int* in_sizes, int n_in,
                              void* d_out, int out_size, void* d_ws, size_t ws_size,
                              hipStream_t stream) {
    const float* A = (const float*)d_in[0];
    const float* P = (const float*)d_in[1];
    float* out = (float*)d_out;

    unsigned short* Abf = (unsigned short*)d_ws;            // N*Dm bf16 = 8 MiB
    unsigned short* Pbf = Abf + (size_t)N * Dm;             // 8 MiB
    float* D     = (float*)(Pbf + (size_t)N * Dm);          // N
    float* rowl2 = D + N;                                   // N
    float* partL = rowl2 + N;                               // NPART
    float* partR = partL + NPART;                           // NPART
    float* Mpart = partR + NPART;                           // N*NCB = 1 MiB
    float* Spart = Mpart + (size_t)N * NCB;                 // 1 MiB

    prep_kernel<<<N / 4, 256, 0, stream>>>(A, P, Abf, Pbf, D, rowl2);
    dim3 grid(N / BN, N / BM);
    npair_mfma<<<grid, 256, 0, stream>>>(Abf, Pbf, D, Mpart, Spart);
    combine_rows<<<N / 8, 256, 0, stream>>>(Mpart, Spart, rowl2, partL, partR);
    final_reduce<<<1, 256, 0, stream>>>(partL, partR, out);
}